// Round 3
// baseline (598.403 us; speedup 1.0000x reference)
//
#include <hip/hip_runtime.h>

typedef __bf16 bf16;
typedef __bf16 bf16x8 __attribute__((ext_vector_type(8)));
typedef float  f32x4  __attribute__((ext_vector_type(4)));

#define MFMA16(a,b,c) __builtin_amdgcn_mfma_f32_16x16x32_bf16((a),(b),(c),0,0,0)

// ---- constants: B=4, S=2048, D=512, H=8, hd=64 ----
#define BATCH 4
#define SEQ   2048
#define DIM   512
#define NH    8
#define HD    64
// 0.125 * log2(e): folded into q at projection time so exp(x*0.125) == exp2(q_scaled . k)
#define QSCALE 0.18033688f

// swizzled LDS tile: [row][64] bf16, 8-elem units XOR'd by (row&7) -> <=2-way banks
__device__ __forceinline__ bf16x8 ldsfrag(const bf16* t, int row, int kc, int quad){
    int unit = ((kc << 2) + quad) ^ (row & 7);
    return *(const bf16x8*)(t + row * 64 + unit * 8);
}

__device__ __forceinline__ void stage64x64(const bf16* src, long rowStride, bf16* dst, int tid){
#pragma unroll
    for (int rnd = 0; rnd < 2; ++rnd){
        int sid = tid + rnd * 256;          // 512 segs of 8 bf16
        int row = sid >> 3, s = sid & 7;
        bf16x8 val = *(const bf16x8*)(src + (long)row * rowStride + s * 8);
        *(bf16x8*)(dst + row * 64 + ((s ^ (row & 7)) << 3)) = val;
    }
}

// ---------------- kernel 0a: x f32 -> bf16 ----------------
__global__ __launch_bounds__(256) void cvt_x(const float* __restrict__ x, bf16* __restrict__ xb){
    int i = blockIdx.x * 256 + threadIdx.x;          // 4194304/4 threads
    float4 f = ((const float4*)x)[i];
    bf16* o = xb + 4 * (long)i;
    o[0] = (bf16)f.x; o[1] = (bf16)f.y; o[2] = (bf16)f.z; o[3] = (bf16)f.w;
}

// ---------------- kernel 0b: W f32 [k][n] -> WT bf16 [n][k] ----------------
__global__ __launch_bounds__(256) void cvt_wt(const float* __restrict__ Wq, const float* __restrict__ Wk,
                                              const float* __restrict__ Wv, const float* __restrict__ Wo,
                                              bf16* __restrict__ WTb){
    int z = blockIdx.z;
    const float* W = (z == 0) ? Wq : (z == 1) ? Wk : (z == 2) ? Wv : Wo;
    bf16* WT = WTb + (long)z * DIM * DIM;
    __shared__ float lt[32 * 33];
    int t = threadIdx.x, r0 = t >> 5, c = t & 31;
    int k0 = blockIdx.x * 32, n0 = blockIdx.y * 32;
#pragma unroll
    for (int i = 0; i < 4; ++i){
        int row = r0 + i * 8;
        lt[row * 33 + c] = W[(long)(k0 + row) * DIM + n0 + c];
    }
    __syncthreads();
#pragma unroll
    for (int i = 0; i < 4; ++i){
        int nr = r0 + i * 8;
        WT[(long)(n0 + nr) * DIM + k0 + c] = (bf16)lt[c * 33 + nr];
    }
}

// ---------------- kernel 1: QKV projection GEMM ----------------
// Y[m][n] = sum_k X[m][k]*W[k][n] + b[n]; out layout [B,H,S,hd] bf16. z picks q/k/v.
// For z==0 (q) the softmax scale * log2(e) is folded into the output.
__global__ __launch_bounds__(256) void gemm_qkv(const bf16* __restrict__ X, const bf16* __restrict__ WTb,
                                                const float* __restrict__ bq, const float* __restrict__ bk,
                                                const float* __restrict__ bv, bf16* __restrict__ outb){
    __shared__ __align__(16) bf16 lA[128 * 64];
    __shared__ __align__(16) bf16 lB[128 * 64];
    int z = blockIdx.z;
    const bf16* WT = WTb + (long)z * DIM * DIM;
    const float* bias = (z == 0) ? bq : (z == 1) ? bk : bv;
    float qs = (z == 0) ? QSCALE : 1.0f;
    bf16* out = outb + (long)z * BATCH * SEQ * DIM;
    int tid = threadIdx.x, lane = tid & 63, w = tid >> 6;
    int wm = w >> 1, wn = w & 1;
    int m0 = blockIdx.y * 128, n0 = blockIdx.x * 128;
    int r16 = lane & 15, quad = lane >> 4;
    f32x4 zz = {0.f, 0.f, 0.f, 0.f};
    f32x4 acc[4][4];
#pragma unroll
    for (int a = 0; a < 4; ++a)
#pragma unroll
        for (int b2 = 0; b2 < 4; ++b2) acc[a][b2] = zz;

    for (int k0 = 0; k0 < DIM; k0 += 64){
        __syncthreads();
#pragma unroll
        for (int rnd = 0; rnd < 4; ++rnd){
            int sid = tid + rnd * 256;       // 1024 segs per tile
            int row = sid >> 3, s = sid & 7;
            *(bf16x8*)(lA + row * 64 + ((s ^ (row & 7)) << 3)) =
                *(const bf16x8*)(X + (long)(m0 + row) * DIM + k0 + s * 8);
            *(bf16x8*)(lB + row * 64 + ((s ^ (row & 7)) << 3)) =
                *(const bf16x8*)(WT + (long)(n0 + row) * DIM + k0 + s * 8);
        }
        __syncthreads();
#pragma unroll
        for (int kc = 0; kc < 2; ++kc){
            bf16x8 aF[4], bF[4];
#pragma unroll
            for (int i = 0; i < 4; ++i){
                aF[i] = ldsfrag(lA, wm * 64 + i * 16 + r16, kc, quad);
                bF[i] = ldsfrag(lB, wn * 64 + i * 16 + r16, kc, quad);
            }
#pragma unroll
            for (int rb = 0; rb < 4; ++rb)
#pragma unroll
                for (int nb = 0; nb < 4; ++nb)
                    acc[rb][nb] = MFMA16(aF[rb], bF[nb], acc[rb][nb]);
        }
    }
#pragma unroll
    for (int nb = 0; nb < 4; ++nb){
        int col = n0 + wn * 64 + nb * 16 + r16;
        float bv_ = bias[col];
        int hh = col >> 6, d = col & 63;
#pragma unroll
        for (int rb = 0; rb < 4; ++rb)
#pragma unroll
            for (int r = 0; r < 4; ++r){
                int row = m0 + wm * 64 + rb * 16 + quad * 4 + r;
                int bb = row >> 11, s = row & 2047;
                out[((long)(bb * NH + hh) * SEQ + s) * HD + d] = (bf16)((acc[rb][nb][r] + bv_) * qs);
            }
    }
}

// ---------------- kernel 1.5: v [B,H,S,hd] -> vT [B,H,hd,S] ----------------
__global__ __launch_bounds__(256) void vtrans(const bf16* __restrict__ v, bf16* __restrict__ vT){
    __shared__ bf16 lt[64 * 72];
    int tid = threadIdx.x;
    int s0 = blockIdx.x * 64;
    int bh = blockIdx.z * NH + blockIdx.y;
#pragma unroll
    for (int rnd = 0; rnd < 2; ++rnd){
        int sid = tid + rnd * 256;
        int row = sid >> 3, sg = sid & 7;
        *(bf16x8*)(lt + row * 72 + sg * 8) =
            *(const bf16x8*)(v + ((long)bh * SEQ + s0 + row) * HD + sg * 8);
    }
    __syncthreads();
#pragma unroll
    for (int rnd = 0; rnd < 2; ++rnd){
        int sid = tid + rnd * 256;
        int d = sid >> 3, sg = sid & 7;
        bf16x8 o;
#pragma unroll
        for (int j = 0; j < 8; ++j) o[j] = lt[(sg * 8 + j) * 72 + d];
        *(bf16x8*)(vT + ((long)bh * HD + d) * SEQ + s0 + sg * 8) = o;
    }
}

// ---------------- kernel 2: flash attention (no-max softmax, q pre-scaled) ----------------
// block = (qtile64, h, b); wave owns 16 q rows. ctx bf16 [B,S,D]; linv f32 [B,H,S].
// T14 async-stage: next j-tile's K/V are loaded into registers BEFORE compute of the
// current tile, and written to LDS after the post-compute barrier (latency hidden).
__global__ __launch_bounds__(256) void attn_flash(const bf16* __restrict__ q, const bf16* __restrict__ k,
                                                  const bf16* __restrict__ vT, bf16* __restrict__ ctx,
                                                  float* __restrict__ linv_g){
    __shared__ __align__(16) bf16 lQ[64 * 64];
    __shared__ __align__(16) bf16 lK[64 * 64];
    __shared__ __align__(16) bf16 lV[64 * 64];
    __shared__ __align__(16) bf16 lP[4][16 * 64];
    int tid = threadIdx.x, lane = tid & 63, w = tid >> 6;
    int h = blockIdx.y, b = blockIdx.z;
    int bh = b * NH + h;
    int q0 = blockIdx.x * 64;
    int r16 = lane & 15, quad = lane >> 4;

    stage64x64(q + ((long)bh * SEQ + q0) * HD, HD, lQ, tid);
    __syncthreads();
    bf16x8 aF0 = ldsfrag(lQ, w * 16 + r16, 0, quad);
    bf16x8 aF1 = ldsfrag(lQ, w * 16 + r16, 1, quad);

    f32x4 zz = {0.f, 0.f, 0.f, 0.f};
    f32x4 ctxacc[4];
    float lsum[4] = {0.f, 0.f, 0.f, 0.f};
#pragma unroll
    for (int cb = 0; cb < 4; ++cb) ctxacc[cb] = zz;

    // staging registers (T14 split)
    int r0_ = tid >> 3, s_ = tid & 7;
    const bf16* kbase = k + (long)bh * SEQ * HD;
    const bf16* vbase = vT + (long)bh * HD * SEQ;
    bf16x8 kr0, kr1, vr0, vr1;

    auto LOADREGS = [&](int j0){
        kr0 = *(const bf16x8*)(kbase + (long)(j0 + r0_) * HD + s_ * 8);
        kr1 = *(const bf16x8*)(kbase + (long)(j0 + r0_ + 32) * HD + s_ * 8);
        vr0 = *(const bf16x8*)(vbase + (long)r0_ * SEQ + j0 + s_ * 8);
        vr1 = *(const bf16x8*)(vbase + (long)(r0_ + 32) * SEQ + j0 + s_ * 8);
    };
    auto WRITELDS = [&](){
        int u = (s_ ^ (r0_ & 7)) << 3;        // (r0_+32)&7 == r0_&7
        *(bf16x8*)(lK + r0_ * 64 + u) = kr0;
        *(bf16x8*)(lK + (r0_ + 32) * 64 + u) = kr1;
        *(bf16x8*)(lV + r0_ * 64 + u) = vr0;
        *(bf16x8*)(lV + (r0_ + 32) * 64 + u) = vr1;
    };
    auto COMPUTE = [&](){
        __builtin_amdgcn_s_setprio(1);
#pragma unroll
        for (int cb = 0; cb < 4; ++cb){
            f32x4 sa = zz;
            sa = MFMA16(aF0, ldsfrag(lK, cb * 16 + r16, 0, quad), sa);
            sa = MFMA16(aF1, ldsfrag(lK, cb * 16 + r16, 1, quad), sa);
#pragma unroll
            for (int r = 0; r < 4; ++r){
                float p = __builtin_amdgcn_exp2f(sa[r]);
                lsum[r] += p;
                int row = quad * 4 + r, col = cb * 16 + r16;
                int unit = (col >> 3) ^ (row & 7);
                lP[w][row * 64 + unit * 8 + (col & 7)] = (bf16)p;
            }
        }
        // lP[w] is wave-private: in-order DS pipe + lgkmcnt drain, no barrier.
        asm volatile("s_waitcnt lgkmcnt(0)" ::: "memory");
        __builtin_amdgcn_sched_barrier(0);   // rule #18: keep MFMA below the wait
#pragma unroll
        for (int kc = 0; kc < 2; ++kc){
            bf16x8 pF = ldsfrag(lP[w], r16, kc, quad);
#pragma unroll
            for (int cb = 0; cb < 4; ++cb)
                ctxacc[cb] = MFMA16(pF, ldsfrag(lV, cb * 16 + r16, kc, quad), ctxacc[cb]);
        }
        __builtin_amdgcn_s_setprio(0);
    };

    LOADREGS(0);
    WRITELDS();
    __syncthreads();
    for (int j0 = 0; j0 < SEQ - 64; j0 += 64){
        LOADREGS(j0 + 64);        // in flight across the whole compute phase
        COMPUTE();
        __syncthreads();          // all waves done reading lK/lV
        WRITELDS();               // compiler inserts the vmcnt wait for kr/vr here
        __syncthreads();          // writes visible
    }
    COMPUTE();

    // reduce row sums over the 16 lanes holding the same rows
#pragma unroll
    for (int m = 1; m < 16; m <<= 1)
#pragma unroll
        for (int r = 0; r < 4; ++r) lsum[r] += __shfl_xor(lsum[r], m, 64);
    float rinv[4];
#pragma unroll
    for (int r = 0; r < 4; ++r) rinv[r] = 1.0f / lsum[r];
#pragma unroll
    for (int cb = 0; cb < 4; ++cb)
#pragma unroll
        for (int r = 0; r < 4; ++r){
            long srow = q0 + w * 16 + quad * 4 + r;
            ctx[((long)b * SEQ + srow) * DIM + h * HD + cb * 16 + r16] = (bf16)(ctxacc[cb][r] * rinv[r]);
        }
    if (r16 == 0)
#pragma unroll
        for (int r = 0; r < 4; ++r)
            linv_g[(long)bh * SEQ + q0 + w * 16 + quad * 4 + r] = rinv[r];
}

// ---------------- kernel 3: avg_attn (heads split across waves + LDS reduce) ----------------
// 4096 blocks = (b4, qt32 of 64 rows, jt32 of 64 keys), XCD-contiguous task ranges
// (per-XCD working set ~3 MB, fits 4 MB L2). Within a block, wave w computes the
// 64x64 tile's partial sum over heads {2w, 2w+1}; waves combine via ds_add_f32 into
// a 16 KB LDS tile; block stores float4 rows (256 B contiguous segments).
// Same total load instructions as the best previous variant, but 4x shorter per-wave
// serial chains and 4x the wave count.
__global__ __launch_bounds__(256) void attn_avg(const bf16* __restrict__ q, const bf16* __restrict__ k,
                                                const float* __restrict__ linv_g, float* __restrict__ avg){
    __shared__ float red[64 * 64];
    int lin  = blockIdx.x + (blockIdx.y << 5) + (blockIdx.z << 10);   // 0..4095
    int task = ((lin & 7) << 9) + (lin >> 3);                         // bijective XCD swizzle
    int qt = task & 31;
    int jt = (task >> 5) & 31;
    int b  = task >> 10;
    int tid = threadIdx.x, lane = tid & 63, w = tid >> 6;
    int r16 = lane & 15, quad = lane >> 4;
    int qbase = qt * 64;
    int j0 = jt * 64;

    // zero the reduction tile (16 f32 per thread)
    {
        f32x4 z4 = {0.f, 0.f, 0.f, 0.f};
#pragma unroll
        for (int i = 0; i < 4; ++i) *(f32x4*)(red + tid * 16 + i * 4) = z4;
    }
    __syncthreads();

    f32x4 zz = {0.f, 0.f, 0.f, 0.f};
    f32x4 psum[4][4];
#pragma unroll
    for (int rb = 0; rb < 4; ++rb)
#pragma unroll
        for (int cb = 0; cb < 4; ++cb) psum[rb][cb] = zz;

#pragma unroll 1
    for (int hp = 0; hp < 2; ++hp){
        int hh = w * 2 + hp;
        long hA = (long)b * NH + hh;
        const bf16*  qh = q + (hA * SEQ + qbase) * HD;
        const bf16*  kh = k + (hA * SEQ + j0) * HD;
        const float* lh = linv_g + hA * SEQ + qbase;

        bf16x8 aF[4][2];
        float4 lvv[4];
#pragma unroll
        for (int rb = 0; rb < 4; ++rb){
            aF[rb][0] = *(const bf16x8*)(qh + (rb * 16 + r16) * HD + quad * 8);
            aF[rb][1] = *(const bf16x8*)(qh + (rb * 16 + r16) * HD + 32 + quad * 8);
            lvv[rb]   = *(const float4*)(lh + rb * 16 + quad * 4);
        }
#pragma unroll
        for (int cb = 0; cb < 4; ++cb){
            bf16x8 bF0 = *(const bf16x8*)(kh + (cb * 16 + r16) * HD + quad * 8);
            bf16x8 bF1 = *(const bf16x8*)(kh + (cb * 16 + r16) * HD + 32 + quad * 8);
#pragma unroll
            for (int rb = 0; rb < 4; ++rb){
                f32x4 sa = MFMA16(aF[rb][0], bF0, zz);
                sa = MFMA16(aF[rb][1], bF1, sa);
#pragma unroll
                for (int r = 0; r < 4; ++r)
                    psum[rb][cb][r] += __builtin_amdgcn_exp2f(sa[r]) * lvv[rb][r];
            }
        }
    }
    // combine the 4 waves' head-partials: ds_add_f32 atomics into the shared tile
#pragma unroll
    for (int rb = 0; rb < 4; ++rb)
#pragma unroll
        for (int cb = 0; cb < 4; ++cb)
#pragma unroll
            for (int r = 0; r < 4; ++r)
                atomicAdd(&red[(rb * 16 + quad * 4 + r) * 64 + cb * 16 + r16], psum[rb][cb][r]);
    __syncthreads();
    // store: 16 threads cover one 256B row segment; 4 rows per pass
#pragma unroll
    for (int i = 0; i < 4; ++i){
        int row = (tid >> 4) + i * 16;
        int c4  = (tid & 15) * 4;
        f32x4 v = *(const f32x4*)(red + row * 64 + c4);
#pragma unroll
        for (int e = 0; e < 4; ++e) v[e] *= 0.125f;
        __builtin_nontemporal_store(v,
            (f32x4*)&avg[((long)b * SEQ + qbase + row) * SEQ + j0 + c4]);
    }
}

// ---------------- kernel 4: output projection ----------------
__global__ __launch_bounds__(256) void gemm_out(const bf16* __restrict__ CTX, const bf16* __restrict__ WT,
                                                const float* __restrict__ bo, float* __restrict__ out){
    __shared__ __align__(16) bf16 lA[128 * 64];
    __shared__ __align__(16) bf16 lB[128 * 64];
    int tid = threadIdx.x, lane = tid & 63, w = tid >> 6;
    int wm = w >> 1, wn = w & 1;
    int m0 = blockIdx.y * 128, n0 = blockIdx.x * 128;
    int r16 = lane & 15, quad = lane >> 4;
    f32x4 zz = {0.f, 0.f, 0.f, 0.f};
    f32x4 acc[4][4];
#pragma unroll
    for (int a = 0; a < 4; ++a)
#pragma unroll
        for (int b2 = 0; b2 < 4; ++b2) acc[a][b2] = zz;

    for (int k0 = 0; k0 < DIM; k0 += 64){
        __syncthreads();
#pragma unroll
        for (int rnd = 0; rnd < 4; ++rnd){
            int sid = tid + rnd * 256;
            int row = sid >> 3, s = sid & 7;
            *(bf16x8*)(lA + row * 64 + ((s ^ (row & 7)) << 3)) =
                *(const bf16x8*)(CTX + (long)(m0 + row) * DIM + k0 + s * 8);
            *(bf16x8*)(lB + row * 64 + ((s ^ (row & 7)) << 3)) =
                *(const bf16x8*)(WT + (long)(n0 + row) * DIM + k0 + s * 8);
        }
        __syncthreads();
#pragma unroll
        for (int kc = 0; kc < 2; ++kc){
            bf16x8 aF[4], bF[4];
#pragma unroll
            for (int i = 0; i < 4; ++i){
                aF[i] = ldsfrag(lA, wm * 64 + i * 16 + r16, kc, quad);
                bF[i] = ldsfrag(lB, wn * 64 + i * 16 + r16, kc, quad);
            }
#pragma unroll
            for (int rb2 = 0; rb2 < 4; ++rb2)
#pragma unroll
                for (int nb = 0; nb < 4; ++nb)
                    acc[rb2][nb] = MFMA16(aF[rb2], bF[nb], acc[rb2][nb]);
        }
    }
#pragma unroll
    for (int nb = 0; nb < 4; ++nb){
        int col = n0 + wn * 64 + nb * 16 + r16;
        float bv_ = bo[col];
#pragma unroll
        for (int rb2 = 0; rb2 < 4; ++rb2)
#pragma unroll
            for (int r = 0; r < 4; ++r){
                int row = m0 + wm * 64 + rb2 * 16 + quad * 4 + r;
                out[(long)row * DIM + col] = acc[rb2][nb][r] + bv_;
            }
    }
}

extern "C" void kernel_launch(void* const* d_in, const int* in_sizes, int n_in,
                              void* d_out, int out_size, void* d_ws, size_t ws_size,
                              hipStream_t stream) {
    const float* x  = (const float*)d_in[0];
    const float* Wq = (const float*)d_in[1];
    const float* bq = (const float*)d_in[2];
    const float* Wk = (const float*)d_in[3];
    const float* bk = (const float*)d_in[4];
    const float* Wv = (const float*)d_in[5];
    const float* bv = (const float*)d_in[6];
    const float* Wo = (const float*)d_in[7];
    const float* bo = (const float*)d_in[8];
    float* out = (float*)d_out;

    char* ws = (char*)d_ws;
    // ws layout (bytes): xb 8.0MB | WT 2MB | q,k,v 3x8MB | vT 8MB | ctx 8MB | linv 256KB  (~50.3 MB)
    bf16*  xb   = (bf16*)(ws);
    bf16*  WT   = (bf16*)(ws + 8388608);
    bf16*  qb   = (bf16*)(ws + 10485760);
    bf16*  kb   = qb + (long)BATCH * SEQ * DIM;
    bf16*  vb   = kb + (long)BATCH * SEQ * DIM;
    bf16*  vT   = (bf16*)(ws + 35651584);
    bf16*  ctx  = (bf16*)(ws + 44040192);
    float* linv = (float*)(ws + 52428800);

    cvt_x    <<<4096, 256, 0, stream>>>(x, xb);
    cvt_wt   <<<dim3(16, 16, 4), 256, 0, stream>>>(Wq, Wk, Wv, Wo, WT);
    gemm_qkv <<<dim3(4, 64, 3), 256, 0, stream>>>(xb, WT, bq, bk, bv, qb);
    vtrans   <<<dim3(32, 8, 4), 256, 0, stream>>>(vb, vT);
    attn_flash<<<dim3(32, 8, 4), 256, 0, stream>>>(qb, kb, vT, ctx, linv);
    attn_avg <<<dim3(32, 32, 4), 256, 0, stream>>>(qb, kb, linv, out + (long)BATCH * SEQ * DIM);
    gemm_out <<<dim3(4, 64), 256, 0, stream>>>(ctx, WT + 3L * DIM * DIM, bo, out);
}

// Round 4
// 251.210 us; speedup vs baseline: 2.3821x; 2.3821x over previous
//
#include <hip/hip_runtime.h>

typedef __bf16 bf16;
typedef __bf16 bf16x8 __attribute__((ext_vector_type(8)));
typedef float  f32x4  __attribute__((ext_vector_type(4)));

#define MFMA16(a,b,c) __builtin_amdgcn_mfma_f32_16x16x32_bf16((a),(b),(c),0,0,0)

// ---- constants: B=4, S=2048, D=512, H=8, hd=64 ----
#define BATCH 4
#define SEQ   2048
#define DIM   512
#define NH    8
#define HD    64
// 0.125 * log2(e): folded into q at projection time so exp(x*0.125) == exp2(q_scaled . k)
#define QSCALE 0.18033688f

// swizzled LDS tile: [row][64] bf16, 8-elem units XOR'd by (row&7) -> <=2-way banks
__device__ __forceinline__ bf16x8 ldsfrag(const bf16* t, int row, int kc, int quad){
    int unit = ((kc << 2) + quad) ^ (row & 7);
    return *(const bf16x8*)(t + row * 64 + unit * 8);
}

__device__ __forceinline__ void stage64x64(const bf16* src, long rowStride, bf16* dst, int tid){
#pragma unroll
    for (int rnd = 0; rnd < 2; ++rnd){
        int sid = tid + rnd * 256;          // 512 segs of 8 bf16
        int row = sid >> 3, s = sid & 7;
        bf16x8 val = *(const bf16x8*)(src + (long)row * rowStride + s * 8);
        *(bf16x8*)(dst + row * 64 + ((s ^ (row & 7)) << 3)) = val;
    }
}

// ---------------- kernel 0a: x f32 -> bf16 ----------------
__global__ __launch_bounds__(256) void cvt_x(const float* __restrict__ x, bf16* __restrict__ xb){
    int i = blockIdx.x * 256 + threadIdx.x;          // 4194304/4 threads
    float4 f = ((const float4*)x)[i];
    bf16* o = xb + 4 * (long)i;
    o[0] = (bf16)f.x; o[1] = (bf16)f.y; o[2] = (bf16)f.z; o[3] = (bf16)f.w;
}

// ---------------- kernel 0b: W f32 [k][n] -> WT bf16 [n][k] ----------------
__global__ __launch_bounds__(256) void cvt_wt(const float* __restrict__ Wq, const float* __restrict__ Wk,
                                              const float* __restrict__ Wv, const float* __restrict__ Wo,
                                              bf16* __restrict__ WTb){
    int z = blockIdx.z;
    const float* W = (z == 0) ? Wq : (z == 1) ? Wk : (z == 2) ? Wv : Wo;
    bf16* WT = WTb + (long)z * DIM * DIM;
    __shared__ float lt[32 * 33];
    int t = threadIdx.x, r0 = t >> 5, c = t & 31;
    int k0 = blockIdx.x * 32, n0 = blockIdx.y * 32;
#pragma unroll
    for (int i = 0; i < 4; ++i){
        int row = r0 + i * 8;
        lt[row * 33 + c] = W[(long)(k0 + row) * DIM + n0 + c];
    }
    __syncthreads();
#pragma unroll
    for (int i = 0; i < 4; ++i){
        int nr = r0 + i * 8;
        WT[(long)(n0 + nr) * DIM + k0 + c] = (bf16)lt[c * 33 + nr];
    }
}

// ---------------- kernel 1: QKV projection GEMM ----------------
// Y[m][n] = sum_k X[m][k]*W[k][n] + b[n]; out layout [B,H,S,hd] bf16. z picks q/k/v.
// For z==0 (q) the softmax scale * log2(e) is folded into the output.
__global__ __launch_bounds__(256) void gemm_qkv(const bf16* __restrict__ X, const bf16* __restrict__ WTb,
                                                const float* __restrict__ bq, const float* __restrict__ bk,
                                                const float* __restrict__ bv, bf16* __restrict__ outb){
    __shared__ __align__(16) bf16 lA[128 * 64];
    __shared__ __align__(16) bf16 lB[128 * 64];
    int z = blockIdx.z;
    const bf16* WT = WTb + (long)z * DIM * DIM;
    const float* bias = (z == 0) ? bq : (z == 1) ? bk : bv;
    float qs = (z == 0) ? QSCALE : 1.0f;
    bf16* out = outb + (long)z * BATCH * SEQ * DIM;
    int tid = threadIdx.x, lane = tid & 63, w = tid >> 6;
    int wm = w >> 1, wn = w & 1;
    int m0 = blockIdx.y * 128, n0 = blockIdx.x * 128;
    int r16 = lane & 15, quad = lane >> 4;
    f32x4 zz = {0.f, 0.f, 0.f, 0.f};
    f32x4 acc[4][4];
#pragma unroll
    for (int a = 0; a < 4; ++a)
#pragma unroll
        for (int b2 = 0; b2 < 4; ++b2) acc[a][b2] = zz;

    for (int k0 = 0; k0 < DIM; k0 += 64){
        __syncthreads();
#pragma unroll
        for (int rnd = 0; rnd < 4; ++rnd){
            int sid = tid + rnd * 256;       // 1024 segs per tile
            int row = sid >> 3, s = sid & 7;
            *(bf16x8*)(lA + row * 64 + ((s ^ (row & 7)) << 3)) =
                *(const bf16x8*)(X + (long)(m0 + row) * DIM + k0 + s * 8);
            *(bf16x8*)(lB + row * 64 + ((s ^ (row & 7)) << 3)) =
                *(const bf16x8*)(WT + (long)(n0 + row) * DIM + k0 + s * 8);
        }
        __syncthreads();
#pragma unroll
        for (int kc = 0; kc < 2; ++kc){
            bf16x8 aF[4], bF[4];
#pragma unroll
            for (int i = 0; i < 4; ++i){
                aF[i] = ldsfrag(lA, wm * 64 + i * 16 + r16, kc, quad);
                bF[i] = ldsfrag(lB, wn * 64 + i * 16 + r16, kc, quad);
            }
#pragma unroll
            for (int rb = 0; rb < 4; ++rb)
#pragma unroll
                for (int nb = 0; nb < 4; ++nb)
                    acc[rb][nb] = MFMA16(aF[rb], bF[nb], acc[rb][nb]);
        }
    }
#pragma unroll
    for (int nb = 0; nb < 4; ++nb){
        int col = n0 + wn * 64 + nb * 16 + r16;
        float bv_ = bias[col];
        int hh = col >> 6, d = col & 63;
#pragma unroll
        for (int rb = 0; rb < 4; ++rb)
#pragma unroll
            for (int r = 0; r < 4; ++r){
                int row = m0 + wm * 64 + rb * 16 + quad * 4 + r;
                int bb = row >> 11, s = row & 2047;
                out[((long)(bb * NH + hh) * SEQ + s) * HD + d] = (bf16)((acc[rb][nb][r] + bv_) * qs);
            }
    }
}

// ---------------- kernel 1.5: v [B,H,S,hd] -> vT [B,H,hd,S] ----------------
__global__ __launch_bounds__(256) void vtrans(const bf16* __restrict__ v, bf16* __restrict__ vT){
    __shared__ bf16 lt[64 * 72];
    int tid = threadIdx.x;
    int s0 = blockIdx.x * 64;
    int bh = blockIdx.z * NH + blockIdx.y;
#pragma unroll
    for (int rnd = 0; rnd < 2; ++rnd){
        int sid = tid + rnd * 256;
        int row = sid >> 3, sg = sid & 7;
        *(bf16x8*)(lt + row * 72 + sg * 8) =
            *(const bf16x8*)(v + ((long)bh * SEQ + s0 + row) * HD + sg * 8);
    }
    __syncthreads();
#pragma unroll
    for (int rnd = 0; rnd < 2; ++rnd){
        int sid = tid + rnd * 256;
        int d = sid >> 3, sg = sid & 7;
        bf16x8 o;
#pragma unroll
        for (int j = 0; j < 8; ++j) o[j] = lt[(sg * 8 + j) * 72 + d];
        *(bf16x8*)(vT + ((long)bh * HD + d) * SEQ + s0 + sg * 8) = o;
    }
}

// ---------------- kernel 2: flash attention (no-max softmax, q pre-scaled) ----------------
// block = (qtile64, h, b); wave owns 16 q rows. ctx bf16 [B,S,D].
// llv_g f32 [B,H,S] stores log2(rinv * 1/8) for the avg kernel's MFMA C-init fold.
// T14 async-stage: next j-tile's K/V loaded to regs before compute, LDS-written after.
__global__ __launch_bounds__(256) void attn_flash(const bf16* __restrict__ q, const bf16* __restrict__ k,
                                                  const bf16* __restrict__ vT, bf16* __restrict__ ctx,
                                                  float* __restrict__ llv_g){
    __shared__ __align__(16) bf16 lQ[64 * 64];
    __shared__ __align__(16) bf16 lK[64 * 64];
    __shared__ __align__(16) bf16 lV[64 * 64];
    __shared__ __align__(16) bf16 lP[4][16 * 64];
    int tid = threadIdx.x, lane = tid & 63, w = tid >> 6;
    int h = blockIdx.y, b = blockIdx.z;
    int bh = b * NH + h;
    int q0 = blockIdx.x * 64;
    int r16 = lane & 15, quad = lane >> 4;

    stage64x64(q + ((long)bh * SEQ + q0) * HD, HD, lQ, tid);
    __syncthreads();
    bf16x8 aF0 = ldsfrag(lQ, w * 16 + r16, 0, quad);
    bf16x8 aF1 = ldsfrag(lQ, w * 16 + r16, 1, quad);

    f32x4 zz = {0.f, 0.f, 0.f, 0.f};
    f32x4 ctxacc[4];
    float lsum[4] = {0.f, 0.f, 0.f, 0.f};
#pragma unroll
    for (int cb = 0; cb < 4; ++cb) ctxacc[cb] = zz;

    // staging registers (T14 split)
    int r0_ = tid >> 3, s_ = tid & 7;
    const bf16* kbase = k + (long)bh * SEQ * HD;
    const bf16* vbase = vT + (long)bh * HD * SEQ;
    bf16x8 kr0, kr1, vr0, vr1;

    auto LOADREGS = [&](int j0){
        kr0 = *(const bf16x8*)(kbase + (long)(j0 + r0_) * HD + s_ * 8);
        kr1 = *(const bf16x8*)(kbase + (long)(j0 + r0_ + 32) * HD + s_ * 8);
        vr0 = *(const bf16x8*)(vbase + (long)r0_ * SEQ + j0 + s_ * 8);
        vr1 = *(const bf16x8*)(vbase + (long)(r0_ + 32) * SEQ + j0 + s_ * 8);
    };
    auto WRITELDS = [&](){
        int u = (s_ ^ (r0_ & 7)) << 3;        // (r0_+32)&7 == r0_&7
        *(bf16x8*)(lK + r0_ * 64 + u) = kr0;
        *(bf16x8*)(lK + (r0_ + 32) * 64 + u) = kr1;
        *(bf16x8*)(lV + r0_ * 64 + u) = vr0;
        *(bf16x8*)(lV + (r0_ + 32) * 64 + u) = vr1;
    };
    auto COMPUTE = [&](){
        __builtin_amdgcn_s_setprio(1);
#pragma unroll
        for (int cb = 0; cb < 4; ++cb){
            f32x4 sa = zz;
            sa = MFMA16(aF0, ldsfrag(lK, cb * 16 + r16, 0, quad), sa);
            sa = MFMA16(aF1, ldsfrag(lK, cb * 16 + r16, 1, quad), sa);
#pragma unroll
            for (int r = 0; r < 4; ++r){
                float p = __builtin_amdgcn_exp2f(sa[r]);
                lsum[r] += p;
                int row = quad * 4 + r, col = cb * 16 + r16;
                int unit = (col >> 3) ^ (row & 7);
                lP[w][row * 64 + unit * 8 + (col & 7)] = (bf16)p;
            }
        }
        // lP[w] is wave-private: in-order DS pipe + lgkmcnt drain, no barrier.
        asm volatile("s_waitcnt lgkmcnt(0)" ::: "memory");
        __builtin_amdgcn_sched_barrier(0);   // rule #18: keep MFMA below the wait
#pragma unroll
        for (int kc = 0; kc < 2; ++kc){
            bf16x8 pF = ldsfrag(lP[w], r16, kc, quad);
#pragma unroll
            for (int cb = 0; cb < 4; ++cb)
                ctxacc[cb] = MFMA16(pF, ldsfrag(lV, cb * 16 + r16, kc, quad), ctxacc[cb]);
        }
        __builtin_amdgcn_s_setprio(0);
    };

    LOADREGS(0);
    WRITELDS();
    __syncthreads();
    for (int j0 = 0; j0 < SEQ - 64; j0 += 64){
        LOADREGS(j0 + 64);        // in flight across the whole compute phase
        COMPUTE();
        __syncthreads();          // all waves done reading lK/lV
        WRITELDS();               // compiler inserts the vmcnt wait for kr/vr here
        __syncthreads();          // writes visible
    }
    COMPUTE();

    // reduce row sums over the 16 lanes holding the same rows
#pragma unroll
    for (int m = 1; m < 16; m <<= 1)
#pragma unroll
        for (int r = 0; r < 4; ++r) lsum[r] += __shfl_xor(lsum[r], m, 64);
    float rinv[4];
#pragma unroll
    for (int r = 0; r < 4; ++r) rinv[r] = 1.0f / lsum[r];
#pragma unroll
    for (int cb = 0; cb < 4; ++cb)
#pragma unroll
        for (int r = 0; r < 4; ++r){
            long srow = q0 + w * 16 + quad * 4 + r;
            ctx[((long)b * SEQ + srow) * DIM + h * HD + cb * 16 + r16] = (bf16)(ctxacc[cb][r] * rinv[r]);
        }
    if (r16 == 0)
#pragma unroll
        for (int r = 0; r < 4; ++r)
            llv_g[(long)bh * SEQ + q0 + w * 16 + quad * 4 + r] = -__log2f(lsum[r]) - 3.0f;
}

// ---------------- kernel 3: avg_attn (LDS-staged mini-GEMM over heads) ----------------
// 4096 blocks = 64q x 64j tiles, XCD-bijective swizzle (per-XCD set ~3 MB, fits L2).
// Per head: stage Q-tile + K-tile into LDS with COALESCED loads (4 VMEM instrs, full
// 128B lines) instead of 16-line fragment gathers from global -> ~20x fewer VMEM
// transactions than the direct-fragment variant. llv = log2(rinv/8) is folded into
// the QK^T accumulator init, so psum += exp2(sa) is the final averaged value.
// Stores: psum -> padded per-wave LDS tile -> 4 f32x4 store instrs, each covering
// 8 rows x one FULL 128B line (write-combine friendly).
__global__ __launch_bounds__(256) void attn_avg(const bf16* __restrict__ q, const bf16* __restrict__ k,
                                                const float* __restrict__ llv_g, float* __restrict__ avg){
    __shared__ __align__(16) bf16 lQ[64 * 64];
    __shared__ __align__(16) bf16 lK[64 * 64];
    __shared__ __align__(16) float lsOut[4][16 * 65];   // per-wave padded transpose buffer
    int lin  = blockIdx.x + (blockIdx.y << 5) + (blockIdx.z << 10);   // 0..4095
    int task = ((lin & 7) << 9) + (lin >> 3);                         // bijective XCD swizzle
    int qt = task & 31;
    int jt = (task >> 5) & 31;
    int b  = task >> 10;
    int tid = threadIdx.x, lane = tid & 63, w = tid >> 6;
    int r16 = lane & 15, quad = lane >> 4;
    int qbase = qt * 64;
    int j0 = jt * 64;

    f32x4 psum[4];
#pragma unroll
    for (int cb = 0; cb < 4; ++cb) psum[cb] = (f32x4){0.f, 0.f, 0.f, 0.f};

#pragma unroll 1
    for (int hh = 0; hh < NH; ++hh){
        long hA = (long)b * NH + hh;
        __syncthreads();                                  // guard LDS reuse
        stage64x64(q + (hA * SEQ + qbase) * HD, HD, lQ, tid);
        stage64x64(k + (hA * SEQ + j0) * HD, HD, lK, tid);
        f32x4 llv = *(const f32x4*)(llv_g + hA * SEQ + qbase + w * 16 + quad * 4);
        __syncthreads();
        bf16x8 aF0 = ldsfrag(lQ, w * 16 + r16, 0, quad);
        bf16x8 aF1 = ldsfrag(lQ, w * 16 + r16, 1, quad);
#pragma unroll
        for (int cb = 0; cb < 4; ++cb){
            f32x4 sa = MFMA16(aF0, ldsfrag(lK, cb * 16 + r16, 0, quad), llv);
            sa = MFMA16(aF1, ldsfrag(lK, cb * 16 + r16, 1, quad), sa);
#pragma unroll
            for (int r = 0; r < 4; ++r)
                psum[cb][r] += __builtin_amdgcn_exp2f(sa[r]);
        }
    }

    // wave-private transpose: psum -> lsOut[w], then line-complete f32x4 stores
#pragma unroll
    for (int cb = 0; cb < 4; ++cb)
#pragma unroll
        for (int r = 0; r < 4; ++r)
            lsOut[w][(quad * 4 + r) * 65 + cb * 16 + r16] = psum[cb][r];
    // ds_write -> ds_read same-wave dependence; compiler inserts the lgkmcnt wait
#pragma unroll
    for (int i = 0; i < 4; ++i){
        int row  = ((i >> 1) << 3) + (lane >> 3);        // strip-local row 0..15
        int col4 = ((i & 1) << 5) + ((lane & 7) << 2);   // f32 col: 0..63
        f32x4 v = *(const f32x4*)(&lsOut[w][row * 65 + col4]);
        __builtin_nontemporal_store(v,
            (f32x4*)&avg[((long)b * SEQ + qbase + w * 16 + row) * SEQ + j0 + col4]);
    }
}

// ---------------- kernel 4: output projection ----------------
__global__ __launch_bounds__(256) void gemm_out(const bf16* __restrict__ CTX, const bf16* __restrict__ WT,
                                                const float* __restrict__ bo, float* __restrict__ out){
    __shared__ __align__(16) bf16 lA[128 * 64];
    __shared__ __align__(16) bf16 lB[128 * 64];
    int tid = threadIdx.x, lane = tid & 63, w = tid >> 6;
    int wm = w >> 1, wn = w & 1;
    int m0 = blockIdx.y * 128, n0 = blockIdx.x * 128;
    int r16 = lane & 15, quad = lane >> 4;
    f32x4 zz = {0.f, 0.f, 0.f, 0.f};
    f32x4 acc[4][4];
#pragma unroll
    for (int a = 0; a < 4; ++a)
#pragma unroll
        for (int b2 = 0; b2 < 4; ++b2) acc[a][b2] = zz;

    for (int k0 = 0; k0 < DIM; k0 += 64){
        __syncthreads();
#pragma unroll
        for (int rnd = 0; rnd < 4; ++rnd){
            int sid = tid + rnd * 256;
            int row = sid >> 3, s = sid & 7;
            *(bf16x8*)(lA + row * 64 + ((s ^ (row & 7)) << 3)) =
                *(const bf16x8*)(CTX + (long)(m0 + row) * DIM + k0 + s * 8);
            *(bf16x8*)(lB + row * 64 + ((s ^ (row & 7)) << 3)) =
                *(const bf16x8*)(WT + (long)(n0 + row) * DIM + k0 + s * 8);
        }
        __syncthreads();
#pragma unroll
        for (int kc = 0; kc < 2; ++kc){
            bf16x8 aF[4], bF[4];
#pragma unroll
            for (int i = 0; i < 4; ++i){
                aF[i] = ldsfrag(lA, wm * 64 + i * 16 + r16, kc, quad);
                bF[i] = ldsfrag(lB, wn * 64 + i * 16 + r16, kc, quad);
            }
#pragma unroll
            for (int rb2 = 0; rb2 < 4; ++rb2)
#pragma unroll
                for (int nb = 0; nb < 4; ++nb)
                    acc[rb2][nb] = MFMA16(aF[rb2], bF[nb], acc[rb2][nb]);
        }
    }
#pragma unroll
    for (int nb = 0; nb < 4; ++nb){
        int col = n0 + wn * 64 + nb * 16 + r16;
        float bv_ = bo[col];
#pragma unroll
        for (int rb2 = 0; rb2 < 4; ++rb2)
#pragma unroll
            for (int r = 0; r < 4; ++r){
                int row = m0 + wm * 64 + rb2 * 16 + quad * 4 + r;
                out[(long)row * DIM + col] = acc[rb2][nb][r] + bv_;
            }
    }
}

extern "C" void kernel_launch(void* const* d_in, const int* in_sizes, int n_in,
                              void* d_out, int out_size, void* d_ws, size_t ws_size,
                              hipStream_t stream) {
    const float* x  = (const float*)d_in[0];
    const float* Wq = (const float*)d_in[1];
    const float* bq = (const float*)d_in[2];
    const float* Wk = (const float*)d_in[3];
    const float* bk = (const float*)d_in[4];
    const float* Wv = (const float*)d_in[5];
    const float* bv = (const float*)d_in[6];
    const float* Wo = (const float*)d_in[7];
    const float* bo = (const float*)d_in[8];
    float* out = (float*)d_out;

    char* ws = (char*)d_ws;
    // ws layout (bytes): xb 8.0MB | WT 2MB | q,k,v 3x8MB | vT 8MB | ctx 8MB | llv 256KB  (~50.3 MB)
    bf16*  xb   = (bf16*)(ws);
    bf16*  WT   = (bf16*)(ws + 8388608);
    bf16*  qb   = (bf16*)(ws + 10485760);
    bf16*  kb   = qb + (long)BATCH * SEQ * DIM;
    bf16*  vb   = kb + (long)BATCH * SEQ * DIM;
    bf16*  vT   = (bf16*)(ws + 35651584);
    bf16*  ctx  = (bf16*)(ws + 44040192);
    float* llv  = (float*)(ws + 52428800);

    cvt_x    <<<4096, 256, 0, stream>>>(x, xb);
    cvt_wt   <<<dim3(16, 16, 4), 256, 0, stream>>>(Wq, Wk, Wv, Wo, WT);
    gemm_qkv <<<dim3(4, 64, 3), 256, 0, stream>>>(xb, WT, bq, bk, bv, qb);
    vtrans   <<<dim3(32, 8, 4), 256, 0, stream>>>(vb, vT);
    attn_flash<<<dim3(32, 8, 4), 256, 0, stream>>>(qb, kb, vT, ctx, llv);
    attn_avg <<<dim3(32, 32, 4), 256, 0, stream>>>(qb, kb, llv, out + (long)BATCH * SEQ * DIM);
    gemm_out <<<dim3(4, 64), 256, 0, stream>>>(ctx, WT + 3L * DIM * DIM, bo, out);
}

// Round 5
// 245.965 us; speedup vs baseline: 2.4329x; 1.0213x over previous
//
#include <hip/hip_runtime.h>

typedef __bf16 bf16;
typedef __bf16 bf16x8 __attribute__((ext_vector_type(8)));
typedef float  f32x4  __attribute__((ext_vector_type(4)));
typedef float  f32x16 __attribute__((ext_vector_type(16)));

#define MFMA16(a,b,c) __builtin_amdgcn_mfma_f32_16x16x32_bf16((a),(b),(c),0,0,0)
#define MFMA32(a,b,c) __builtin_amdgcn_mfma_f32_32x32x16_bf16((a),(b),(c),0,0,0)

// ---- constants: B=4, S=2048, D=512, H=8, hd=64 ----
#define BATCH 4
#define SEQ   2048
#define DIM   512
#define NH    8
#define HD    64
// 0.125 * log2(e): folded into q at projection time so exp(x*0.125) == exp2(q_scaled . k)
#define QSCALE 0.18033688f

// swizzled LDS tile: [row][64] bf16, 8-elem units XOR'd by (row&7) -> even bank spread
__device__ __forceinline__ bf16x8 ldsfrag(const bf16* t, int row, int kc, int quad){
    int unit = ((kc << 2) + quad) ^ (row & 7);
    return *(const bf16x8*)(t + row * 64 + unit * 8);
}
// same swizzle, unit given directly (for 32x32 fragment reads)
__device__ __forceinline__ bf16x8 ldsfrag32(const bf16* t, int row, int unit){
    return *(const bf16x8*)(t + row * 64 + ((unit ^ (row & 7)) << 3));
}

__device__ __forceinline__ void stage64x64(const bf16* src, long rowStride, bf16* dst, int tid){
#pragma unroll
    for (int rnd = 0; rnd < 2; ++rnd){
        int sid = tid + rnd * 256;          // 512 segs of 8 bf16
        int row = sid >> 3, s = sid & 7;
        bf16x8 val = *(const bf16x8*)(src + (long)row * rowStride + s * 8);
        *(bf16x8*)(dst + row * 64 + ((s ^ (row & 7)) << 3)) = val;
    }
}

// ---------------- kernel 0a: x f32 -> bf16 ----------------
__global__ __launch_bounds__(256) void cvt_x(const float* __restrict__ x, bf16* __restrict__ xb){
    int i = blockIdx.x * 256 + threadIdx.x;
    float4 f = ((const float4*)x)[i];
    bf16* o = xb + 4 * (long)i;
    o[0] = (bf16)f.x; o[1] = (bf16)f.y; o[2] = (bf16)f.z; o[3] = (bf16)f.w;
}

// ---------------- kernel 0b: W f32 [k][n] -> WT bf16 [n][k] ----------------
__global__ __launch_bounds__(256) void cvt_wt(const float* __restrict__ Wq, const float* __restrict__ Wk,
                                              const float* __restrict__ Wv, const float* __restrict__ Wo,
                                              bf16* __restrict__ WTb){
    int z = blockIdx.z;
    const float* W = (z == 0) ? Wq : (z == 1) ? Wk : (z == 2) ? Wv : Wo;
    bf16* WT = WTb + (long)z * DIM * DIM;
    __shared__ float lt[32 * 33];
    int t = threadIdx.x, r0 = t >> 5, c = t & 31;
    int k0 = blockIdx.x * 32, n0 = blockIdx.y * 32;
#pragma unroll
    for (int i = 0; i < 4; ++i){
        int row = r0 + i * 8;
        lt[row * 33 + c] = W[(long)(k0 + row) * DIM + n0 + c];
    }
    __syncthreads();
#pragma unroll
    for (int i = 0; i < 4; ++i){
        int nr = r0 + i * 8;
        WT[(long)(n0 + nr) * DIM + k0 + c] = (bf16)lt[c * 33 + nr];
    }
}

// ---------------- kernel 1: QKV projection GEMM ----------------
__global__ __launch_bounds__(256) void gemm_qkv(const bf16* __restrict__ X, const bf16* __restrict__ WTb,
                                                const float* __restrict__ bq, const float* __restrict__ bk,
                                                const float* __restrict__ bv, bf16* __restrict__ outb){
    __shared__ __align__(16) bf16 lA[128 * 64];
    __shared__ __align__(16) bf16 lB[128 * 64];
    int z = blockIdx.z;
    const bf16* WT = WTb + (long)z * DIM * DIM;
    const float* bias = (z == 0) ? bq : (z == 1) ? bk : bv;
    float qs = (z == 0) ? QSCALE : 1.0f;
    bf16* out = outb + (long)z * BATCH * SEQ * DIM;
    int tid = threadIdx.x, lane = tid & 63, w = tid >> 6;
    int wm = w >> 1, wn = w & 1;
    int m0 = blockIdx.y * 128, n0 = blockIdx.x * 128;
    int r16 = lane & 15, quad = lane >> 4;
    f32x4 zz = {0.f, 0.f, 0.f, 0.f};
    f32x4 acc[4][4];
#pragma unroll
    for (int a = 0; a < 4; ++a)
#pragma unroll
        for (int b2 = 0; b2 < 4; ++b2) acc[a][b2] = zz;

    for (int k0 = 0; k0 < DIM; k0 += 64){
        __syncthreads();
#pragma unroll
        for (int rnd = 0; rnd < 4; ++rnd){
            int sid = tid + rnd * 256;
            int row = sid >> 3, s = sid & 7;
            *(bf16x8*)(lA + row * 64 + ((s ^ (row & 7)) << 3)) =
                *(const bf16x8*)(X + (long)(m0 + row) * DIM + k0 + s * 8);
            *(bf16x8*)(lB + row * 64 + ((s ^ (row & 7)) << 3)) =
                *(const bf16x8*)(WT + (long)(n0 + row) * DIM + k0 + s * 8);
        }
        __syncthreads();
#pragma unroll
        for (int kc = 0; kc < 2; ++kc){
            bf16x8 aF[4], bF[4];
#pragma unroll
            for (int i = 0; i < 4; ++i){
                aF[i] = ldsfrag(lA, wm * 64 + i * 16 + r16, kc, quad);
                bF[i] = ldsfrag(lB, wn * 64 + i * 16 + r16, kc, quad);
            }
#pragma unroll
            for (int rb = 0; rb < 4; ++rb)
#pragma unroll
                for (int nb = 0; nb < 4; ++nb)
                    acc[rb][nb] = MFMA16(aF[rb], bF[nb], acc[rb][nb]);
        }
    }
#pragma unroll
    for (int nb = 0; nb < 4; ++nb){
        int col = n0 + wn * 64 + nb * 16 + r16;
        float bv_ = bias[col];
        int hh = col >> 6, d = col & 63;
#pragma unroll
        for (int rb = 0; rb < 4; ++rb)
#pragma unroll
            for (int r = 0; r < 4; ++r){
                int row = m0 + wm * 64 + rb * 16 + quad * 4 + r;
                int bb = row >> 11, s = row & 2047;
                out[((long)(bb * NH + hh) * SEQ + s) * HD + d] = (bf16)((acc[rb][nb][r] + bv_) * qs);
            }
    }
}

// ---------------- kernel 1.5: v [B,H,S,hd] -> vT [B,H,hd,S] ----------------
__global__ __launch_bounds__(256) void vtrans(const bf16* __restrict__ v, bf16* __restrict__ vT){
    __shared__ bf16 lt[64 * 72];
    int tid = threadIdx.x;
    int s0 = blockIdx.x * 64;
    int bh = blockIdx.z * NH + blockIdx.y;
#pragma unroll
    for (int rnd = 0; rnd < 2; ++rnd){
        int sid = tid + rnd * 256;
        int row = sid >> 3, sg = sid & 7;
        *(bf16x8*)(lt + row * 72 + sg * 8) =
            *(const bf16x8*)(v + ((long)bh * SEQ + s0 + row) * HD + sg * 8);
    }
    __syncthreads();
#pragma unroll
    for (int rnd = 0; rnd < 2; ++rnd){
        int sid = tid + rnd * 256;
        int d = sid >> 3, sg = sid & 7;
        bf16x8 o;
#pragma unroll
        for (int j = 0; j < 8; ++j) o[j] = lt[(sg * 8 + j) * 72 + d];
        *(bf16x8*)(vT + ((long)bh * HD + d) * SEQ + s0 + sg * 8) = o;
    }
}

// ---------------- kernel 2: flash attention, 32x32 MFMA ----------------
// block = 4 waves, q-tile 128 (wave owns 32 q-rows x all 64 d). j-tiles of 64 keys.
// 32x32x16 halves LDS fragment bytes per FLOP vs 16x16x32 (2KB/32KFLOP).
// C/D layout (m74/m101): col=lane&31, row=(reg&3)+8*(reg>>2)+4*(lane>>5).
// A/B frag: row/col = lane&31, k = (lane>>5)*8 + e within each 16-k slice.
// Grid XCD-swizzled so each XCD holds 4 heads' K/V (2MB, fits L2).
__global__ __launch_bounds__(256) void attn_flash(const bf16* __restrict__ q, const bf16* __restrict__ k,
                                                  const bf16* __restrict__ vT, bf16* __restrict__ ctx,
                                                  float* __restrict__ llv_g){
    __shared__ __align__(16) bf16 lQ[128 * 64];
    __shared__ __align__(16) bf16 lK[64 * 64];
    __shared__ __align__(16) bf16 lV[64 * 64];
    __shared__ __align__(16) bf16 lP[4][32 * 64];
    int tid = threadIdx.x, lane = tid & 63, w = tid >> 6;
    int lin = blockIdx.x + (blockIdx.y << 4) + (blockIdx.z << 7);    // 0..511
    int task = ((lin & 7) << 6) + (lin >> 3);                        // bijective XCD swizzle
    int qt = task & 15, h = (task >> 4) & 7, b = task >> 7;
    int bh = b * NH + h;
    int q0 = qt * 128;
    int row32 = lane & 31, half = lane >> 5;
    int r3 = row32 >> 3, c7 = row32 & 7;

    // stage Q 128x64 (swizzled)
    {
        const bf16* src = q + ((long)bh * SEQ + q0) * HD;
#pragma unroll
        for (int rnd = 0; rnd < 4; ++rnd){
            int sid = tid + rnd * 256;
            int row = sid >> 3, s = sid & 7;
            *(bf16x8*)(lQ + row * 64 + ((s ^ (row & 7)) << 3)) =
                *(const bf16x8*)(src + (long)row * HD + s * 8);
        }
    }
    __syncthreads();
    bf16x8 qF[4];
#pragma unroll
    for (int s = 0; s < 4; ++s) qF[s] = ldsfrag32(lQ, w * 32 + row32, 2 * s + half);

    f32x16 ctxacc[2];
    float lsum[16];
#pragma unroll
    for (int i = 0; i < 16; ++i){ ctxacc[0][i] = 0.f; ctxacc[1][i] = 0.f; lsum[i] = 0.f; }

    // staging registers (T14 split)
    int r0_ = tid >> 3, s_ = tid & 7;
    const bf16* kbase = k + (long)bh * SEQ * HD;
    const bf16* vbase = vT + (long)bh * HD * SEQ;
    bf16x8 kr0, kr1, vr0, vr1;
    bf16* lPw = lP[w];

    auto LOADREGS = [&](int j0){
        kr0 = *(const bf16x8*)(kbase + (long)(j0 + r0_) * HD + s_ * 8);
        kr1 = *(const bf16x8*)(kbase + (long)(j0 + r0_ + 32) * HD + s_ * 8);
        vr0 = *(const bf16x8*)(vbase + (long)r0_ * SEQ + j0 + s_ * 8);
        vr1 = *(const bf16x8*)(vbase + (long)(r0_ + 32) * SEQ + j0 + s_ * 8);
    };
    auto WRITELDS = [&](){
        int u = (s_ ^ (r0_ & 7)) << 3;
        *(bf16x8*)(lK + r0_ * 64 + u) = kr0;
        *(bf16x8*)(lK + (r0_ + 32) * 64 + u) = kr1;
        *(bf16x8*)(lV + r0_ * 64 + u) = vr0;
        *(bf16x8*)(lV + (r0_ + 32) * 64 + u) = vr1;
    };
    auto COMPUTE = [&](){
        __builtin_amdgcn_s_setprio(1);
        // QK^T: D[q32][key32] per key-block; P written to wave-private swizzled LDS
#pragma unroll
        for (int kb = 0; kb < 2; ++kb){
            f32x16 sacc;
#pragma unroll
            for (int i = 0; i < 16; ++i) sacc[i] = 0.f;
#pragma unroll
            for (int s = 0; s < 4; ++s)
                sacc = MFMA32(qF[s], ldsfrag32(lK, kb * 32 + row32, 2 * s + half), sacc);
#pragma unroll
            for (int reg = 0; reg < 16; ++reg){
                float pp = __builtin_amdgcn_exp2f(sacc[reg]);
                lsum[reg] += pp;
                int qr = (reg & 3) + 8 * (reg >> 2) + 4 * half;
                int pu = ((kb ^ half) << 2) | (r3 ^ (reg & 3));     // = (col>>3) ^ (qr&7)
                lPw[qr * 64 + pu * 8 + c7] = (bf16)pp;
            }
        }
        // lP[w] is wave-private: in-order DS pipe + lgkmcnt drain, no barrier.
        asm volatile("s_waitcnt lgkmcnt(0)" ::: "memory");
        __builtin_amdgcn_sched_barrier(0);   // rule #18: keep MFMA below the wait
        bf16x8 pF[4];
#pragma unroll
        for (int ks = 0; ks < 4; ++ks) pF[ks] = ldsfrag32(lPw, row32, 2 * ks + half);
#pragma unroll
        for (int db = 0; db < 2; ++db)
#pragma unroll
            for (int ks = 0; ks < 4; ++ks)
                ctxacc[db] = MFMA32(pF[ks], ldsfrag32(lV, db * 32 + row32, 2 * ks + half), ctxacc[db]);
        __builtin_amdgcn_s_setprio(0);
    };

    LOADREGS(0);
    WRITELDS();
    __syncthreads();
    for (int j0 = 0; j0 < SEQ - 64; j0 += 64){
        LOADREGS(j0 + 64);        // in flight across the whole compute phase
        COMPUTE();
        __syncthreads();          // all waves done reading lK/lV
        WRITELDS();               // compiler inserts the vmcnt wait here
        __syncthreads();          // writes visible
    }
    COMPUTE();

    // reduce row sums over the 32 lanes of each half (keys are spread across them)
#pragma unroll
    for (int m = 1; m < 32; m <<= 1)
#pragma unroll
        for (int reg = 0; reg < 16; ++reg) lsum[reg] += __shfl_xor(lsum[reg], m, 64);
    float rinv[16];
#pragma unroll
    for (int reg = 0; reg < 16; ++reg) rinv[reg] = 1.0f / lsum[reg];
#pragma unroll
    for (int db = 0; db < 2; ++db)
#pragma unroll
        for (int reg = 0; reg < 16; ++reg){
            int qr = (reg & 3) + 8 * (reg >> 2) + 4 * half;
            long srow = q0 + w * 32 + qr;
            ctx[((long)b * SEQ + srow) * DIM + h * HD + db * 32 + row32] =
                (bf16)(ctxacc[db][reg] * rinv[reg]);
        }
    if (row32 == 0)
#pragma unroll
        for (int reg = 0; reg < 16; ++reg){
            int qr = (reg & 3) + 8 * (reg >> 2) + 4 * half;
            llv_g[(long)bh * SEQ + q0 + w * 32 + qr] = -__log2f(lsum[reg]) - 3.0f;
        }
}

// ---------------- kernel 3: avg_attn (LDS-staged mini-GEMM over heads, T14 prefetch) ----------------
__global__ __launch_bounds__(256) void attn_avg(const bf16* __restrict__ q, const bf16* __restrict__ k,
                                                const float* __restrict__ llv_g, float* __restrict__ avg){
    __shared__ __align__(16) bf16 lQ[64 * 64];
    __shared__ __align__(16) bf16 lK[64 * 64];
    __shared__ __align__(16) float lsOut[4][16 * 65];   // per-wave padded transpose buffer
    int lin  = blockIdx.x + (blockIdx.y << 5) + (blockIdx.z << 10);   // 0..4095
    int task = ((lin & 7) << 9) + (lin >> 3);                         // bijective XCD swizzle
    int qt = task & 31;
    int jt = (task >> 5) & 31;
    int b  = task >> 10;
    int tid = threadIdx.x, lane = tid & 63, w = tid >> 6;
    int r16 = lane & 15, quad = lane >> 4;
    int qbase = qt * 64;
    int j0 = jt * 64;

    // T14 split staging: issue next head's loads during current head's compute
    int r0_ = tid >> 3, s_ = tid & 7;
    int u_ = (s_ ^ (r0_ & 7)) << 3;
    bf16x8 qr0, qr1, kr0, kr1;
    auto LOADA = [&](int hh){
        long hA = (long)b * NH + hh;
        const bf16* qh = q + (hA * SEQ + qbase) * HD;
        const bf16* kh = k + (hA * SEQ + j0) * HD;
        qr0 = *(const bf16x8*)(qh + (long)r0_ * HD + s_ * 8);
        qr1 = *(const bf16x8*)(qh + (long)(r0_ + 32) * HD + s_ * 8);
        kr0 = *(const bf16x8*)(kh + (long)r0_ * HD + s_ * 8);
        kr1 = *(const bf16x8*)(kh + (long)(r0_ + 32) * HD + s_ * 8);
    };
    auto WRITEA = [&](){
        *(bf16x8*)(lQ + r0_ * 64 + u_) = qr0;
        *(bf16x8*)(lQ + (r0_ + 32) * 64 + u_) = qr1;
        *(bf16x8*)(lK + r0_ * 64 + u_) = kr0;
        *(bf16x8*)(lK + (r0_ + 32) * 64 + u_) = kr1;
    };

    f32x4 psum[4];
#pragma unroll
    for (int cb = 0; cb < 4; ++cb) psum[cb] = (f32x4){0.f, 0.f, 0.f, 0.f};

    LOADA(0);
    WRITEA();
    __syncthreads();
#pragma unroll 1
    for (int hh = 0; hh < NH; ++hh){
        if (hh < NH - 1) LOADA(hh + 1);          // global loads in flight over compute
        f32x4 llv = *(const f32x4*)(llv_g + ((long)b * NH + hh) * SEQ + qbase + w * 16 + quad * 4);
        bf16x8 aF0 = ldsfrag(lQ, w * 16 + r16, 0, quad);
        bf16x8 aF1 = ldsfrag(lQ, w * 16 + r16, 1, quad);
#pragma unroll
        for (int cb = 0; cb < 4; ++cb){
            f32x4 sa = MFMA16(aF0, ldsfrag(lK, cb * 16 + r16, 0, quad), llv);
            sa = MFMA16(aF1, ldsfrag(lK, cb * 16 + r16, 1, quad), sa);
#pragma unroll
            for (int r = 0; r < 4; ++r)
                psum[cb][r] += __builtin_amdgcn_exp2f(sa[r]);
        }
        __syncthreads();                          // all reads of lQ/lK done
        if (hh < NH - 1){
            WRITEA();                             // vmcnt wait inserted by compiler
            __syncthreads();                      // writes visible
        }
    }

    // wave-private transpose: psum -> lsOut[w], then line-complete f32x4 stores
#pragma unroll
    for (int cb = 0; cb < 4; ++cb)
#pragma unroll
        for (int r = 0; r < 4; ++r)
            lsOut[w][(quad * 4 + r) * 65 + cb * 16 + r16] = psum[cb][r];
#pragma unroll
    for (int i = 0; i < 4; ++i){
        int row  = ((i >> 1) << 3) + (lane >> 3);        // strip-local row 0..15
        int col4 = ((i & 1) << 5) + ((lane & 7) << 2);   // f32 col: 0..63
        f32x4 v = *(const f32x4*)(&lsOut[w][row * 65 + col4]);
        __builtin_nontemporal_store(v,
            (f32x4*)&avg[((long)b * SEQ + qbase + w * 16 + row) * SEQ + j0 + col4]);
    }
}

// ---------------- kernel 4: output projection ----------------
__global__ __launch_bounds__(256) void gemm_out(const bf16* __restrict__ CTX, const bf16* __restrict__ WT,
                                                const float* __restrict__ bo, float* __restrict__ out){
    __shared__ __align__(16) bf16 lA[128 * 64];
    __shared__ __align__(16) bf16 lB[128 * 64];
    int tid = threadIdx.x, lane = tid & 63, w = tid >> 6;
    int wm = w >> 1, wn = w & 1;
    int m0 = blockIdx.y * 128, n0 = blockIdx.x * 128;
    int r16 = lane & 15, quad = lane >> 4;
    f32x4 zz = {0.f, 0.f, 0.f, 0.f};
    f32x4 acc[4][4];
#pragma unroll
    for (int a = 0; a < 4; ++a)
#pragma unroll
        for (int b2 = 0; b2 < 4; ++b2) acc[a][b2] = zz;

    for (int k0 = 0; k0 < DIM; k0 += 64){
        __syncthreads();
#pragma unroll
        for (int rnd = 0; rnd < 4; ++rnd){
            int sid = tid + rnd * 256;
            int row = sid >> 3, s = sid & 7;
            *(bf16x8*)(lA + row * 64 + ((s ^ (row & 7)) << 3)) =
                *(const bf16x8*)(CTX + (long)(m0 + row) * DIM + k0 + s * 8);
            *(bf16x8*)(lB + row * 64 + ((s ^ (row & 7)) << 3)) =
                *(const bf16x8*)(WT + (long)(n0 + row) * DIM + k0 + s * 8);
        }
        __syncthreads();
#pragma unroll
        for (int kc = 0; kc < 2; ++kc){
            bf16x8 aF[4], bF[4];
#pragma unroll
            for (int i = 0; i < 4; ++i){
                aF[i] = ldsfrag(lA, wm * 64 + i * 16 + r16, kc, quad);
                bF[i] = ldsfrag(lB, wn * 64 + i * 16 + r16, kc, quad);
            }
#pragma unroll
            for (int rb2 = 0; rb2 < 4; ++rb2)
#pragma unroll
                for (int nb = 0; nb < 4; ++nb)
                    acc[rb2][nb] = MFMA16(aF[rb2], bF[nb], acc[rb2][nb]);
        }
    }
#pragma unroll
    for (int nb = 0; nb < 4; ++nb){
        int col = n0 + wn * 64 + nb * 16 + r16;
        float bv_ = bo[col];
#pragma unroll
        for (int rb2 = 0; rb2 < 4; ++rb2)
#pragma unroll
            for (int r = 0; r < 4; ++r){
                int row = m0 + wm * 64 + rb2 * 16 + quad * 4 + r;
                out[(long)row * DIM + col] = acc[rb2][nb][r] + bv_;
            }
    }
}

extern "C" void kernel_launch(void* const* d_in, const int* in_sizes, int n_in,
                              void* d_out, int out_size, void* d_ws, size_t ws_size,
                              hipStream_t stream) {
    const float* x  = (const float*)d_in[0];
    const float* Wq = (const float*)d_in[1];
    const float* bq = (const float*)d_in[2];
    const float* Wk = (const float*)d_in[3];
    const float* bk = (const float*)d_in[4];
    const float* Wv = (const float*)d_in[5];
    const float* bv = (const float*)d_in[6];
    const float* Wo = (const float*)d_in[7];
    const float* bo = (const float*)d_in[8];
    float* out = (float*)d_out;

    char* ws = (char*)d_ws;
    // ws layout (bytes): xb 8.0MB | WT 2MB | q,k,v 3x8MB | vT 8MB | ctx 8MB | llv 256KB
    bf16*  xb   = (bf16*)(ws);
    bf16*  WT   = (bf16*)(ws + 8388608);
    bf16*  qb   = (bf16*)(ws + 10485760);
    bf16*  kb   = qb + (long)BATCH * SEQ * DIM;
    bf16*  vb   = kb + (long)BATCH * SEQ * DIM;
    bf16*  vT   = (bf16*)(ws + 35651584);
    bf16*  ctx  = (bf16*)(ws + 44040192);
    float* llv  = (float*)(ws + 52428800);

    cvt_x    <<<4096, 256, 0, stream>>>(x, xb);
    cvt_wt   <<<dim3(16, 16, 4), 256, 0, stream>>>(Wq, Wk, Wv, Wo, WT);
    gemm_qkv <<<dim3(4, 64, 3), 256, 0, stream>>>(xb, WT, bq, bk, bv, qb);
    vtrans   <<<dim3(32, 8, 4), 256, 0, stream>>>(vb, vT);
    attn_flash<<<dim3(16, 8, 4), 256, 0, stream>>>(qb, kb, vT, ctx, llv);
    attn_avg <<<dim3(32, 32, 4), 256, 0, stream>>>(qb, kb, llv, out + (long)BATCH * SEQ * DIM);
    gemm_out <<<dim3(4, 64), 256, 0, stream>>>(ctx, WT + 3L * DIM * DIM, bo, out);
}